// Round 1
// baseline (2324.535 us; speedup 1.0000x reference)
//
#include <hip/hip_runtime.h>
#include <hip/hip_bf16.h>
#include <math.h>

// Problem constants
#define S_LEN 2048
#define NHEAD 16
#define HDIM 64
#define EMB 1024
#define NBATCH 2
#define MROWS (NBATCH * S_LEN)      // 4096
#define BH 32                        // NBATCH*NHEAD
#define QKV_T ((size_t)BH * S_LEN * HDIM)  // elems per projected tensor = 4194304
#define W_ELEMS ((size_t)S_LEN * S_LEN * BH) // 134217728 per copy
#define OUT_ELEMS ((size_t)MROWS * EMB)      // 4194304

typedef __bf16 bf16x8 __attribute__((ext_vector_type(8)));
typedef float f32x4 __attribute__((ext_vector_type(4)));

__device__ inline unsigned short f2bf(float f) {
    unsigned int u = __float_as_uint(f);
    unsigned int r = (u + 0x7fffu + ((u >> 16) & 1u)) >> 16;
    return (unsigned short)r;
}

// ---------------- f32 -> bf16 conversion ----------------
__global__ __launch_bounds__(256) void conv_bf16_k(const float* __restrict__ src,
                                                   unsigned short* __restrict__ dst, int n4) {
    int i = blockIdx.x * 256 + threadIdx.x;
    if (i < n4) {
        float4 v = ((const float4*)src)[i];
        ushort4 o;
        o.x = f2bf(v.x); o.y = f2bf(v.y); o.z = f2bf(v.z); o.w = f2bf(v.w);
        ((ushort4*)dst)[i] = o;
    }
}

// ---------------- projection GEMM: Y = X * W^T, fused RoPE epilogue ----------------
// X: (4096,1024) bf16 row-major. W: (1024,1024) bf16 row-major (f,e). 6 GEMMs via blockIdx.z.
// Output: bf16 (bh, s, d) layout per tensor g in {Q1,K1,V1,Q2,K2,V2}.
__global__ __launch_bounds__(256) void gemm_proj_k(const unsigned short* __restrict__ qb,
                                                   const unsigned short* __restrict__ kb,
                                                   const unsigned short* __restrict__ vb,
                                                   const unsigned short* __restrict__ wb,
                                                   unsigned short* __restrict__ qkv) {
    __shared__ unsigned short As[128][72];
    __shared__ unsigned short Bs[128][72];
    int g = blockIdx.z;
    int sel = g % 3;
    const unsigned short* X = sel == 0 ? qb : (sel == 1 ? kb : vb);
    const unsigned short* W = wb + (size_t)g * (EMB * EMB);
    unsigned short* Y = qkv + (size_t)g * QKV_T;
    bool rope = sel < 2;

    int bm = blockIdx.y, bn = blockIdx.x;
    int tid = threadIdx.x;
    int wid = tid >> 6, lane = tid & 63;
    int wm = wid >> 1, wn = wid & 1;
    int col = lane & 15, quad = lane >> 4;

    f32x4 acc[4][4] = {};

    for (int k0 = 0; k0 < EMB; k0 += 64) {
        int4 ar[4], br[4];
#pragma unroll
        for (int c = 0; c < 4; c++) {
            int cid = c * 256 + tid;
            int row = cid >> 3, cc = (cid & 7) * 8;
            ar[c] = *(const int4*)(X + (size_t)(bm * 128 + row) * EMB + k0 + cc);
            br[c] = *(const int4*)(W + (size_t)(bn * 128 + row) * EMB + k0 + cc);
        }
        __syncthreads();
#pragma unroll
        for (int c = 0; c < 4; c++) {
            int cid = c * 256 + tid;
            int row = cid >> 3, cc = (cid & 7) * 8;
            *(int4*)(&As[row][cc]) = ar[c];
            *(int4*)(&Bs[row][cc]) = br[c];
        }
        __syncthreads();
#pragma unroll
        for (int kk = 0; kk < 64; kk += 32) {
            bf16x8 af[4], bf[4];
#pragma unroll
            for (int i = 0; i < 4; i++)
                af[i] = *(const bf16x8*)(&As[wm * 64 + i * 16 + col][kk + quad * 8]);
#pragma unroll
            for (int i = 0; i < 4; i++)
                bf[i] = *(const bf16x8*)(&Bs[wn * 64 + i * 16 + col][kk + quad * 8]);
#pragma unroll
            for (int i = 0; i < 4; i++)
#pragma unroll
                for (int j = 0; j < 4; j++)
                    acc[i][j] = __builtin_amdgcn_mfma_f32_16x16x32_bf16(af[i], bf[j], acc[i][j], 0, 0, 0);
        }
        __syncthreads();
    }

    int h = bn * 2 + wn;  // wave covers exactly one head's 64 cols
#pragma unroll
    for (int mi = 0; mi < 4; mi++) {
#pragma unroll
        for (int r = 0; r < 4; r++) {
            int m = bm * 128 + wm * 64 + mi * 16 + quad * 4 + r;
            int b = m >> 11, s = m & (S_LEN - 1);
            unsigned short* Yrow = Y + ((size_t)(b * NHEAD + h) * S_LEN + s) * HDIM;
            if (rope) {
#pragma unroll
                for (int ni = 0; ni < 2; ni++) {
                    int d1 = ni * 16 + col;
                    float x1 = acc[mi][ni][r];
                    float x2 = acc[mi][ni + 2][r];
                    float inv_freq = powf(10000.f, -(float)d1 * (1.0f / 32.0f));
                    float ang = (float)s * inv_freq;
                    float sn, cs;
                    sincosf(ang, &sn, &cs);
                    Yrow[d1] = f2bf(x1 * cs - x2 * sn);
                    Yrow[d1 + 32] = f2bf(x1 * sn + x2 * cs);
                }
            } else {
#pragma unroll
                for (int ni = 0; ni < 4; ni++)
                    Yrow[ni * 16 + col] = f2bf(acc[mi][ni][r]);
            }
        }
    }
}

// ---------------- V transpose: (bh,s,d) -> (bh,d,s) per copy ----------------
__global__ __launch_bounds__(256) void vtrans_k(const unsigned short* __restrict__ qkv,
                                                unsigned short* __restrict__ vt) {
    __shared__ unsigned short t[64][65];
    int copy = blockIdx.z, bh = blockIdx.y;
    int s0 = blockIdx.x * 64;
    const unsigned short* V = qkv + (size_t)(copy * 3 + 2) * QKV_T + (size_t)bh * S_LEN * HDIM;
    unsigned short* VT = vt + (size_t)copy * QKV_T + (size_t)bh * HDIM * S_LEN;
    int tid = threadIdx.x;
#pragma unroll
    for (int c = 0; c < 16; c++) {
        int idx = c * 256 + tid;
        int sl = idx >> 6, d = idx & 63;
        t[sl][d] = V[(size_t)(s0 + sl) * HDIM + d];
    }
    __syncthreads();
#pragma unroll
    for (int c = 0; c < 16; c++) {
        int idx = c * 256 + tid;
        int dl = idx >> 6, sl = idx & 63;
        VT[(size_t)dl * S_LEN + s0 + sl] = t[sl][dl];
    }
}

// ---------------- attention QK^T + softmax, writes w (f32) ----------------
// grid: (32 q-tiles of 64, 64 combos). Each wave: 16 q-rows. Two-pass online softmax.
__global__ __launch_bounds__(256) void attn_qk_k(const unsigned short* __restrict__ qkv,
                                                 float* __restrict__ wout_base) {
    int qt = blockIdx.x;
    int combo = blockIdx.y;
    int copy = combo >> 5, bh = combo & 31;
    const unsigned short* Q = qkv + (size_t)(copy * 3 + 0) * QKV_T + (size_t)bh * S_LEN * HDIM;
    const unsigned short* K = qkv + (size_t)(copy * 3 + 1) * QKV_T + (size_t)bh * S_LEN * HDIM;
    float* Wout = wout_base + (size_t)copy * W_ELEMS + (size_t)bh * S_LEN * S_LEN;

    int wid = threadIdx.x >> 6, lane = threadIdx.x & 63;
    int col = lane & 15, quad = lane >> 4;
    int q0 = qt * 64 + wid * 16;

    const unsigned short* qrow = Q + (size_t)(q0 + col) * HDIM;
    bf16x8 a0 = *(const bf16x8*)(qrow + quad * 8);
    bf16x8 a1 = *(const bf16x8*)(qrow + 32 + quad * 8);

    int ktmax = qt * 4 + 3;
    const float NEG = -1e30f;
    float mloc[4] = {NEG, NEG, NEG, NEG};
    float lloc[4] = {0.f, 0.f, 0.f, 0.f};

    // Pass 1: lane-local online (m,l) over this lane's column subset
    for (int kt = 0; kt <= ktmax; kt++) {
        const unsigned short* krow = K + (size_t)(kt * 16 + col) * HDIM;
        bf16x8 b0 = *(const bf16x8*)(krow + quad * 8);
        bf16x8 b1 = *(const bf16x8*)(krow + 32 + quad * 8);
        f32x4 c = {};
        c = __builtin_amdgcn_mfma_f32_16x16x32_bf16(a0, b0, c, 0, 0, 0);
        c = __builtin_amdgcn_mfma_f32_16x16x32_bf16(a1, b1, c, 0, 0, 0);
        int kg = kt * 16 + col;
#pragma unroll
        for (int r = 0; r < 4; r++) {
            int qg = q0 + quad * 4 + r;
            if (kg <= qg) {
                float s = c[r] * 0.125f;
                float mn = fmaxf(mloc[r], s);
                lloc[r] = lloc[r] * __expf(mloc[r] - mn) + __expf(s - mn);
                mloc[r] = mn;
            }
        }
    }
    // Butterfly merge (m,l) across the 16 lanes holding each row
    float mrow[4], invl[4];
#pragma unroll
    for (int r = 0; r < 4; r++) {
        float m = mloc[r], l = lloc[r];
#pragma unroll
        for (int off = 1; off < 16; off <<= 1) {
            float m2 = __shfl_xor(m, off);
            float l2 = __shfl_xor(l, off);
            float mn = fmaxf(m, m2);
            l = l * __expf(m - mn) + l2 * __expf(m2 - mn);
            m = mn;
        }
        mrow[r] = m;
        invl[r] = 1.f / l;
    }
    // Pass 2: recompute scores, write w (zeros above diagonal and beyond)
    for (int kt = 0; kt < (S_LEN / 16); kt++) {
        int kg = kt * 16 + col;
        float wv[4];
        if (kt <= ktmax) {
            const unsigned short* krow = K + (size_t)(kt * 16 + col) * HDIM;
            bf16x8 b0 = *(const bf16x8*)(krow + quad * 8);
            bf16x8 b1 = *(const bf16x8*)(krow + 32 + quad * 8);
            f32x4 c = {};
            c = __builtin_amdgcn_mfma_f32_16x16x32_bf16(a0, b0, c, 0, 0, 0);
            c = __builtin_amdgcn_mfma_f32_16x16x32_bf16(a1, b1, c, 0, 0, 0);
#pragma unroll
            for (int r = 0; r < 4; r++) {
                int qg = q0 + quad * 4 + r;
                float s = c[r] * 0.125f;
                wv[r] = (kg <= qg) ? __expf(s - mrow[r]) * invl[r] : 0.f;
            }
        } else {
#pragma unroll
            for (int r = 0; r < 4; r++) wv[r] = 0.f;
        }
#pragma unroll
        for (int r = 0; r < 4; r++)
            Wout[(size_t)(q0 + quad * 4 + r) * S_LEN + kg] = wv[r];
    }
}

// ---------------- PV: ctx = w * V, writes ctx f32 in (b,s,h*64+d) layout ----------------
__global__ __launch_bounds__(256) void attn_pv_k(const float* __restrict__ wbuf_base,
                                                 const unsigned short* __restrict__ vt,
                                                 float* __restrict__ ctx) {
    int qt = blockIdx.x;
    int combo = blockIdx.y;
    int copy = combo >> 5, bh = combo & 31;
    int b = bh >> 4, h = bh & 15;
    const float* Wb = wbuf_base + (size_t)copy * W_ELEMS + (size_t)bh * S_LEN * S_LEN;
    const unsigned short* VT = vt + (size_t)copy * QKV_T + (size_t)bh * HDIM * S_LEN;
    float* C = ctx + (size_t)copy * OUT_ELEMS;

    int wid = threadIdx.x >> 6, lane = threadIdx.x & 63;
    int col = lane & 15, quad = lane >> 4;
    int q0 = qt * 64 + wid * 16;

    f32x4 acc[4] = {};
    int ktm = qt * 2 + 1;
    for (int kt = 0; kt <= ktm; kt++) {
        const float* wr = Wb + (size_t)(q0 + col) * S_LEN + kt * 32 + quad * 8;
        float4 lo = *(const float4*)wr;
        float4 hi = *(const float4*)(wr + 4);
        union { unsigned short u[8]; bf16x8 v; } cv;
        cv.u[0] = f2bf(lo.x); cv.u[1] = f2bf(lo.y); cv.u[2] = f2bf(lo.z); cv.u[3] = f2bf(lo.w);
        cv.u[4] = f2bf(hi.x); cv.u[5] = f2bf(hi.y); cv.u[6] = f2bf(hi.z); cv.u[7] = f2bf(hi.w);
        bf16x8 a = cv.v;
#pragma unroll
        for (int ni = 0; ni < 4; ni++) {
            const unsigned short* vr = VT + (size_t)(ni * 16 + col) * S_LEN + kt * 32 + quad * 8;
            bf16x8 bv = *(const bf16x8*)vr;
            acc[ni] = __builtin_amdgcn_mfma_f32_16x16x32_bf16(a, bv, acc[ni], 0, 0, 0);
        }
    }
#pragma unroll
    for (int ni = 0; ni < 4; ni++)
#pragma unroll
        for (int r = 0; r < 4; r++) {
            int qg = q0 + quad * 4 + r;
            C[((size_t)(b * S_LEN + qg)) * EMB + h * HDIM + ni * 16 + col] = acc[ni][r];
        }
}

// ---------------- ctx1*ctx2 -> bf16 ----------------
__global__ __launch_bounds__(256) void mulcvt_k(const float* __restrict__ c1,
                                                const float* __restrict__ c2,
                                                unsigned short* __restrict__ o, int n4) {
    int i = blockIdx.x * 256 + threadIdx.x;
    if (i < n4) {
        float4 a = ((const float4*)c1)[i];
        float4 b = ((const float4*)c2)[i];
        ushort4 ov;
        ov.x = f2bf(a.x * b.x); ov.y = f2bf(a.y * b.y);
        ov.z = f2bf(a.z * b.z); ov.w = f2bf(a.w * b.w);
        ((ushort4*)o)[i] = ov;
    }
}

// ---------------- output GEMM: out = ctxP * WO^T (f32 out) ----------------
__global__ __launch_bounds__(256) void gemm_out_k(const unsigned short* __restrict__ A,
                                                  const unsigned short* __restrict__ W,
                                                  float* __restrict__ out) {
    __shared__ unsigned short As[128][72];
    __shared__ unsigned short Bs[128][72];
    int bm = blockIdx.y, bn = blockIdx.x;
    int tid = threadIdx.x;
    int wid = tid >> 6, lane = tid & 63;
    int wm = wid >> 1, wn = wid & 1;
    int col = lane & 15, quad = lane >> 4;

    f32x4 acc[4][4] = {};

    for (int k0 = 0; k0 < EMB; k0 += 64) {
        int4 ar[4], br[4];
#pragma unroll
        for (int c = 0; c < 4; c++) {
            int cid = c * 256 + tid;
            int row = cid >> 3, cc = (cid & 7) * 8;
            ar[c] = *(const int4*)(A + (size_t)(bm * 128 + row) * EMB + k0 + cc);
            br[c] = *(const int4*)(W + (size_t)(bn * 128 + row) * EMB + k0 + cc);
        }
        __syncthreads();
#pragma unroll
        for (int c = 0; c < 4; c++) {
            int cid = c * 256 + tid;
            int row = cid >> 3, cc = (cid & 7) * 8;
            *(int4*)(&As[row][cc]) = ar[c];
            *(int4*)(&Bs[row][cc]) = br[c];
        }
        __syncthreads();
#pragma unroll
        for (int kk = 0; kk < 64; kk += 32) {
            bf16x8 af[4], bf[4];
#pragma unroll
            for (int i = 0; i < 4; i++)
                af[i] = *(const bf16x8*)(&As[wm * 64 + i * 16 + col][kk + quad * 8]);
#pragma unroll
            for (int i = 0; i < 4; i++)
                bf[i] = *(const bf16x8*)(&Bs[wn * 64 + i * 16 + col][kk + quad * 8]);
#pragma unroll
            for (int i = 0; i < 4; i++)
#pragma unroll
                for (int j = 0; j < 4; j++)
                    acc[i][j] = __builtin_amdgcn_mfma_f32_16x16x32_bf16(af[i], bf[j], acc[i][j], 0, 0, 0);
        }
        __syncthreads();
    }
#pragma unroll
    for (int mi = 0; mi < 4; mi++)
#pragma unroll
        for (int ni = 0; ni < 4; ni++)
#pragma unroll
            for (int r = 0; r < 4; r++) {
                int m = bm * 128 + wm * 64 + mi * 16 + quad * 4 + r;
                int n = bn * 128 + wn * 64 + ni * 16 + col;
                out[(size_t)m * EMB + n] = acc[mi][ni][r];
            }
}

extern "C" void kernel_launch(void* const* d_in, const int* in_sizes, int n_in,
                              void* d_out, int out_size, void* d_ws, size_t ws_size,
                              hipStream_t stream) {
    const float* q = (const float*)d_in[0];
    const float* k = (const float*)d_in[1];
    const float* v = (const float*)d_in[2];
    // d_in[3] = mask (causal tril) — hard-coded in kernels

    char* ws = (char*)d_ws;
    size_t off = 0;
    auto alloc = [&](size_t bytes) -> void* {
        void* p = ws + off;
        off += (bytes + 255) & ~(size_t)255;
        return p;
    };
    unsigned short* qb = (unsigned short*)alloc(OUT_ELEMS * 2);
    unsigned short* kb = (unsigned short*)alloc(OUT_ELEMS * 2);
    unsigned short* vb = (unsigned short*)alloc(OUT_ELEMS * 2);
    unsigned short* wb = (unsigned short*)alloc((size_t)7 * EMB * EMB * 2);
    unsigned short* qkv = (unsigned short*)alloc((size_t)6 * QKV_T * 2);
    unsigned short* vt = (unsigned short*)alloc((size_t)2 * QKV_T * 2);
    float* ctx = (float*)alloc((size_t)2 * OUT_ELEMS * 4);
    unsigned short* ctxp = (unsigned short*)alloc(OUT_ELEMS * 2);

    // 1. dtype conversions
    conv_bf16_k<<<OUT_ELEMS / 4 / 256, 256, 0, stream>>>(q, qb, OUT_ELEMS / 4);
    conv_bf16_k<<<OUT_ELEMS / 4 / 256, 256, 0, stream>>>(k, kb, OUT_ELEMS / 4);
    conv_bf16_k<<<OUT_ELEMS / 4 / 256, 256, 0, stream>>>(v, vb, OUT_ELEMS / 4);
    for (int i = 0; i < 7; i++)
        conv_bf16_k<<<(EMB * EMB) / 4 / 256, 256, 0, stream>>>(
            (const float*)d_in[4 + i], wb + (size_t)i * EMB * EMB, (EMB * EMB) / 4);

    // 2. projections + RoPE
    gemm_proj_k<<<dim3(8, 32, 6), 256, 0, stream>>>(qb, kb, vb, wb, qkv);
    // 3. V transpose
    vtrans_k<<<dim3(32, 32, 2), 256, 0, stream>>>(qkv, vt);

    float* wout = (float*)d_out + OUT_ELEMS;  // w1 then w2
    // 4. QK^T + softmax -> w
    attn_qk_k<<<dim3(32, 64), 256, 0, stream>>>(qkv, wout);
    // 5. PV -> ctx
    attn_pv_k<<<dim3(32, 64), 256, 0, stream>>>(wout, vt, ctx);
    // 6. ctx1*ctx2 -> bf16
    mulcvt_k<<<OUT_ELEMS / 4 / 256, 256, 0, stream>>>(ctx, ctx + OUT_ELEMS, ctxp, OUT_ELEMS / 4);
    // 7. output projection
    gemm_out_k<<<dim3(8, 32), 256, 0, stream>>>(ctxp, wb + (size_t)6 * EMB * EMB, (float*)d_out);
}